// Round 2
// baseline (441.652 us; speedup 1.0000x reference)
//
#include <hip/hip_runtime.h>
#include <math.h>

// WaveletKANClassifier, MI355X gfx950. ALL inputs/outputs are FLOAT32
// (round-1 NaN proved it: fp32 read as bf16 -> NaN patterns; threshold
// 0.1075 = 2% * 5.375 shows the bf16 floor path was inactive).
//
// K0: pack W,Wc -> bf16; Wp -> bf16 hi/lo split  (into d_ws)
// K1: wi = x@Wp^T via split-bf16 3-MFMA (err ~5e-6); haar cells within
//     2e-4 of a step boundary get an exact fp64 VALU recheck. Writes
//     wav = gelu(wavelet(s)) as bf16 into d_ws.
// K2: h = x@W^T + wav@Wc^T (+biases); fused LayerNorm; f32 out.
//     bf16 MFMA ok: est absmax err ~0.03 << 0.1075 threshold.

#define B_SZ  32768
#define DIN   768
#define DOUT  768
#define NWAV  48

// d_ws layout (units: shorts/bf16)
#define WB_OFF   0          // W   bf16: 768*768 = 589824
#define WCB_OFF  589824     // Wc  bf16: 768*48  = 36864
#define WPH_OFF  626688     // Wp  hi  : 48*768  = 36864
#define WPL_OFF  663552     // Wp  lo  : 48*768  = 36864
#define WAV_OFF  700416     // wav bf16: 32768*48 = 1572864

typedef short bf16x8 __attribute__((ext_vector_type(8)));
typedef float f32x4  __attribute__((ext_vector_type(4)));

__device__ __forceinline__ float bf2f(short u) {
    union { unsigned int i; float f; } v;
    v.i = ((unsigned int)(unsigned short)u) << 16;
    return v.f;
}
__device__ __forceinline__ short f2bf(float f) {
    union { float f; unsigned int i; } v; v.f = f;
    unsigned int r = v.i + 0x7FFFu + ((v.i >> 16) & 1u);  // RNE
    return (short)(r >> 16);
}

// ---------------------------------------------------------------- K0: pack
__global__ __launch_bounds__(256) void pack_kernel(
    const float* __restrict__ W, const float* __restrict__ Wc,
    const float* __restrict__ Wp, short* __restrict__ ws)
{
    const int i = blockIdx.x * 256 + threadIdx.x;
    if (i < DOUT * DIN) ws[WB_OFF + i] = f2bf(W[i]);
    if (i < DOUT * NWAV) ws[WCB_OFF + i] = f2bf(Wc[i]);
    if (i < NWAV * DIN) {
        const float w = Wp[i];
        const short h = f2bf(w);
        ws[WPH_OFF + i] = h;
        ws[WPL_OFF + i] = f2bf(w - bf2f(h));
    }
}

// ---------------------------------------------------------------- K1: wav
__global__ __launch_bounds__(256) void wav_kernel(
    const float* __restrict__ x, const float* __restrict__ Wp,
    const float* __restrict__ bp, const float* __restrict__ scales,
    const float* __restrict__ trans, short* __restrict__ ws)
{
    __shared__ __align__(16) short Ah[64 * 40];  // 64 rows x 32k bf16-hi
    __shared__ __align__(16) short Al[64 * 40];  // bf16-lo

    const short* Wph = ws + WPH_OFF;
    const short* Wpl = ws + WPL_OFF;
    short* wav = ws + WAV_OFF;

    const int tid  = threadIdx.x;
    const int r0   = blockIdx.x * 64;
    const int wave = tid >> 6, lane = tid & 63;
    const int n = lane & 15, q = lane >> 4;

    f32x4 acc[3];
    const f32x4 zero4 = {0.f, 0.f, 0.f, 0.f};
#pragma unroll
    for (int t = 0; t < 3; t++) acc[t] = zero4;

    const int srow = tid >> 2, sch = tid & 3;
    for (int k0 = 0; k0 < DIN; k0 += 32) {
        __syncthreads();
        {
            const float4 v0 = *reinterpret_cast<const float4*>(
                &x[(size_t)(r0 + srow) * DIN + k0 + sch * 8]);
            const float4 v1 = *reinterpret_cast<const float4*>(
                &x[(size_t)(r0 + srow) * DIN + k0 + sch * 8 + 4]);
            float f[8] = {v0.x, v0.y, v0.z, v0.w, v1.x, v1.y, v1.z, v1.w};
            bf16x8 hh, ll;
#pragma unroll
            for (int i = 0; i < 8; i++) {
                const short h = f2bf(f[i]);
                hh[i] = h;
                ll[i] = f2bf(f[i] - bf2f(h));
            }
            *reinterpret_cast<bf16x8*>(&Ah[srow * 40 + sch * 8]) = hh;
            *reinterpret_cast<bf16x8*>(&Al[srow * 40 + sch * 8]) = ll;
        }
        __syncthreads();
        const bf16x8 ah = *reinterpret_cast<bf16x8*>(&Ah[(wave * 16 + n) * 40 + q * 8]);
        const bf16x8 al = *reinterpret_cast<bf16x8*>(&Al[(wave * 16 + n) * 40 + q * 8]);
#pragma unroll
        for (int t = 0; t < 3; t++) {
            const bf16x8 bh = *reinterpret_cast<const bf16x8*>(&Wph[(size_t)(t * 16 + n) * DIN + k0 + q * 8]);
            const bf16x8 bl = *reinterpret_cast<const bf16x8*>(&Wpl[(size_t)(t * 16 + n) * DIN + k0 + q * 8]);
            acc[t] = __builtin_amdgcn_mfma_f32_16x16x32_bf16(ah, bl, acc[t], 0, 0, 0);
            acc[t] = __builtin_amdgcn_mfma_f32_16x16x32_bf16(al, bh, acc[t], 0, 0, 0);
            acc[t] = __builtin_amdgcn_mfma_f32_16x16x32_bf16(ah, bh, acc[t], 0, 0, 0);
        }
    }

#pragma unroll
    for (int t = 0; t < 3; t++) {
        const int j = t * 16 + n;
        const float bpv = bp[j];
        const float scv = scales[j];
        const float trv = trans[j];
#pragma unroll
        for (int r = 0; r < 4; r++) {
            const int row = r0 + wave * 16 + q * 4 + r;
            const float wi = acc[t][r] + bpv;
            const float s  = (wi - trv) / scv;
            float w;
            if (t == 0) {
                // haar step: boundary-safe. err(wi) ~ 5e-6; flag at 2e-4.
                const float dmin = fminf(fabsf(s), fminf(fabsf(s - 0.5f), fabsf(s - 1.0f)));
                if (dmin < 2e-4f) {
                    const float* xr = &x[(size_t)row * DIN];
                    const float* wr = &Wp[(size_t)j * DIN];
                    double a0 = 0.0, a1 = 0.0, a2 = 0.0, a3 = 0.0;
                    for (int k = 0; k < DIN; k += 4) {
                        a0 = fma((double)xr[k + 0], (double)wr[k + 0], a0);
                        a1 = fma((double)xr[k + 1], (double)wr[k + 1], a1);
                        a2 = fma((double)xr[k + 2], (double)wr[k + 2], a2);
                        a3 = fma((double)xr[k + 3], (double)wr[k + 3], a3);
                    }
                    const double wid = ((a0 + a1) + (a2 + a3)) + (double)bpv;
                    const double sd  = (wid - (double)trv) / (double)scv;
                    w = (sd >= 0.0 && sd < 0.5) ? 1.f : ((sd >= 0.5 && sd < 1.0) ? -1.f : 0.f);
                } else {
                    w = (s >= 0.f && s < 0.5f) ? 1.f : ((s >= 0.5f && s < 1.f) ? -1.f : 0.f);
                }
            } else if (t == 1) {
                w = (1.f - s * s) * expf(-0.5f * s * s);
            } else {
                w = cosf(5.f * s) * expf(-0.5f * s * s);
            }
            const float g = 0.5f * w * (1.f + erff(w * 0.70710678118654752f));
            wav[(size_t)row * NWAV + j] = f2bf(g);
        }
    }
}

// ---------------------------------------------------------------- K2: main
__global__ __launch_bounds__(512) void main_kernel(
    const float* __restrict__ x, const short* __restrict__ ws,
    const float* __restrict__ bb, const float* __restrict__ bc,
    const float* __restrict__ gamma, const float* __restrict__ beta,
    float* __restrict__ out)
{
    __shared__ __align__(16) short As[64 * 72];  // 64 rows x 64k, stride 72
    __shared__ float redS[64 * 4];
    __shared__ float redQ[64 * 4];
    __shared__ float muA[64];
    __shared__ float rsA[64];

    const short* Wb  = ws + WB_OFF;
    const short* Wcb = ws + WCB_OFF;
    const short* wavg = ws + WAV_OFF;

    const int tid  = threadIdx.x;
    const int r0   = blockIdx.x * 64;
    const int wave = tid >> 6, lane = tid & 63;
    const int n = lane & 15, q = lane >> 4;
    const int wm = wave >> 2, wn = wave & 3;
    const int colbase = wn * 192;

    f32x4 acc[2][12];
    const f32x4 zero4 = {0.f, 0.f, 0.f, 0.f};
#pragma unroll
    for (int rt = 0; rt < 2; rt++)
#pragma unroll
        for (int ct = 0; ct < 12; ct++) acc[rt][ct] = zero4;

    const int srow = tid >> 3, sch = tid & 7;
    for (int k0 = 0; k0 < DIN; k0 += 64) {
        __syncthreads();
        {
            const float4 v0 = *reinterpret_cast<const float4*>(
                &x[(size_t)(r0 + srow) * DIN + k0 + sch * 8]);
            const float4 v1 = *reinterpret_cast<const float4*>(
                &x[(size_t)(r0 + srow) * DIN + k0 + sch * 8 + 4]);
            bf16x8 hh;
            hh[0] = f2bf(v0.x); hh[1] = f2bf(v0.y); hh[2] = f2bf(v0.z); hh[3] = f2bf(v0.w);
            hh[4] = f2bf(v1.x); hh[5] = f2bf(v1.y); hh[6] = f2bf(v1.z); hh[7] = f2bf(v1.w);
            *reinterpret_cast<bf16x8*>(&As[srow * 72 + sch * 8]) = hh;
        }
        __syncthreads();
#pragma unroll
        for (int kk = 0; kk < 64; kk += 32) {
            const bf16x8 a0 = *reinterpret_cast<bf16x8*>(&As[(wm * 32 + n) * 72 + kk + q * 8]);
            const bf16x8 a1 = *reinterpret_cast<bf16x8*>(&As[(wm * 32 + 16 + n) * 72 + kk + q * 8]);
#pragma unroll
            for (int ct = 0; ct < 12; ct++) {
                const int col = colbase + ct * 16 + n;
                const bf16x8 b = *reinterpret_cast<const bf16x8*>(&Wb[(size_t)col * DIN + k0 + kk + q * 8]);
                acc[0][ct] = __builtin_amdgcn_mfma_f32_16x16x32_bf16(a0, b, acc[0][ct], 0, 0, 0);
                acc[1][ct] = __builtin_amdgcn_mfma_f32_16x16x32_bf16(a1, b, acc[1][ct], 0, 0, 0);
            }
        }
    }

    // ---- wavelet path: h += wav @ Wc^T  (K=48 padded to 64 with zeros)
    __syncthreads();
    if (tid < 384) {
        const int row = tid / 6, ch = tid % 6;
        *reinterpret_cast<int4*>(&As[row * 72 + ch * 8]) =
            *reinterpret_cast<const int4*>(&wavg[(size_t)(r0 + row) * NWAV + ch * 8]);
    } else {
        const int i2 = tid - 384;
        const int row = i2 >> 1, h = i2 & 1;
        int4 zz; zz.x = 0; zz.y = 0; zz.z = 0; zz.w = 0;
        *reinterpret_cast<int4*>(&As[row * 72 + 48 + h * 8]) = zz;
    }
    __syncthreads();
#pragma unroll
    for (int kk = 0; kk < 64; kk += 32) {
        const bf16x8 a0 = *reinterpret_cast<bf16x8*>(&As[(wm * 32 + n) * 72 + kk + q * 8]);
        const bf16x8 a1 = *reinterpret_cast<bf16x8*>(&As[(wm * 32 + 16 + n) * 72 + kk + q * 8]);
#pragma unroll
        for (int ct = 0; ct < 12; ct++) {
            const int col = colbase + ct * 16 + n;
            bf16x8 b;
            if (kk == 0 || q < 2) {
                b = *reinterpret_cast<const bf16x8*>(&Wcb[(size_t)col * NWAV + kk + q * 8]);
            } else {
                b = (bf16x8){0, 0, 0, 0, 0, 0, 0, 0};  // k >= 48: A is zero anyway
            }
            acc[0][ct] = __builtin_amdgcn_mfma_f32_16x16x32_bf16(a0, b, acc[0][ct], 0, 0, 0);
            acc[1][ct] = __builtin_amdgcn_mfma_f32_16x16x32_bf16(a1, b, acc[1][ct], 0, 0, 0);
        }
    }

    // ---- bias
#pragma unroll
    for (int ct = 0; ct < 12; ct++) {
        const int col = colbase + ct * 16 + n;
        const float bias = bb[col] + bc[col];
#pragma unroll
        for (int rt = 0; rt < 2; rt++)
#pragma unroll
            for (int r = 0; r < 4; r++) acc[rt][ct][r] += bias;
    }

    // ---- LN row reduction (quad shuffle -> LDS cross-wave)
#pragma unroll
    for (int rt = 0; rt < 2; rt++) {
#pragma unroll
        for (int r = 0; r < 4; r++) {
            float s1 = 0.f, s2 = 0.f;
#pragma unroll
            for (int ct = 0; ct < 12; ct++) {
                const float v = acc[rt][ct][r];
                s1 += v; s2 += v * v;
            }
            s1 += __shfl_xor(s1, 1); s1 += __shfl_xor(s1, 2);
            s1 += __shfl_xor(s1, 4); s1 += __shfl_xor(s1, 8);
            s2 += __shfl_xor(s2, 1); s2 += __shfl_xor(s2, 2);
            s2 += __shfl_xor(s2, 4); s2 += __shfl_xor(s2, 8);
            if (n == 0) {
                const int lrow = wm * 32 + rt * 16 + q * 4 + r;
                redS[lrow * 4 + wn] = s1;
                redQ[lrow * 4 + wn] = s2;
            }
        }
    }
    __syncthreads();
    if (tid < 64) {
        const float S = redS[tid * 4] + redS[tid * 4 + 1] + redS[tid * 4 + 2] + redS[tid * 4 + 3];
        const float Q = redQ[tid * 4] + redQ[tid * 4 + 1] + redQ[tid * 4 + 2] + redQ[tid * 4 + 3];
        const float mu = S * (1.f / 768.f);
        const float var = Q * (1.f / 768.f) - mu * mu;
        muA[tid] = mu;
        rsA[tid] = rsqrtf(var + 1e-5f);
    }
    __syncthreads();

    // ---- normalize + store (f32)
    float mu_[2][4], rs_[2][4];
#pragma unroll
    for (int rt = 0; rt < 2; rt++)
#pragma unroll
        for (int r = 0; r < 4; r++) {
            const int lrow = wm * 32 + rt * 16 + q * 4 + r;
            mu_[rt][r] = muA[lrow];
            rs_[rt][r] = rsA[lrow];
        }
#pragma unroll
    for (int ct = 0; ct < 12; ct++) {
        const int col = colbase + ct * 16 + n;
        const float g  = gamma[col];
        const float be = beta[col];
#pragma unroll
        for (int rt = 0; rt < 2; rt++) {
#pragma unroll
            for (int r = 0; r < 4; r++) {
                const int lrow = wm * 32 + rt * 16 + q * 4 + r;
                const float v = (acc[rt][ct][r] - mu_[rt][r]) * rs_[rt][r] * g + be;
                out[(size_t)(r0 + lrow) * DOUT + col] = v;
            }
        }
    }
}

// ---------------------------------------------------------------- launcher
extern "C" void kernel_launch(void* const* d_in, const int* in_sizes, int n_in,
                              void* d_out, int out_size, void* d_ws, size_t ws_size,
                              hipStream_t stream)
{
    const float* x  = (const float*)d_in[0];
    const float* W  = (const float*)d_in[1];
    const float* b  = (const float*)d_in[2];
    const float* Wp = (const float*)d_in[3];
    const float* bp = (const float*)d_in[4];
    const float* Wc = (const float*)d_in[5];
    const float* bc = (const float*)d_in[6];
    const float* sc = (const float*)d_in[7];
    const float* tr = (const float*)d_in[8];
    const float* gm = (const float*)d_in[9];
    const float* bt = (const float*)d_in[10];
    float* out = (float*)d_out;
    short* ws  = (short*)d_ws;   // needs ~4.6 MB

    pack_kernel<<<dim3((DOUT * DIN + 255) / 256), dim3(256), 0, stream>>>(W, Wc, Wp, ws);
    wav_kernel<<<dim3(B_SZ / 64), dim3(256), 0, stream>>>(x, Wp, bp, sc, tr, ws);
    main_kernel<<<dim3(B_SZ / 64), dim3(512), 0, stream>>>(x, ws, b, bc, gm, bt, out);
}

// Round 3
// 307.098 us; speedup vs baseline: 1.4381x; 1.4381x over previous
//
#include <hip/hip_runtime.h>
#include <math.h>

// WaveletKANClassifier, MI355X gfx950. fp32 I/O, bf16 MFMA compute.
//
// Round-3 redesign (round-2 was TA-gather-bound: MfmaUtil 7.9%, 16-segment
// B-fragment gathers at ~7 cyc/line):
//  K0 pack: W, Wp(hi/lo split), Wc -> MFMA-fragment-major bf16 in d_ws, so
//           every B-fragment load is base + lane*16B (coalesced L2 burst).
//  K1 fused: per block 64 rows x 768 cols, 512 thr (8 waves x [64r x 96c]),
//           32x32x16 bf16 MFMA (2x FLOP/byte of 16x16x32).
//           x staged f32->bf16 hi(+lo) into double-buffered LDS.
//           waves 0-3 also compute wi = x@Wp^T via split-bf16 (3 MFMA);
//           wavelet+GELU in-register; wav -> LDS -> A-frags -> @Wc^T;
//           fused LayerNorm epilogue; haar fp64 boundary recheck (2e-4).

#define B_SZ  32768
#define DIN   768
#define DOUT  768
#define NWAV  48

// d_ws fragment-major layout (units: shorts). Fragment tile = 64 lanes x 8
// bf16 = 512 shorts; lane L holds M[c0+(L&31)][k0 + (L>>5)*8 + j].
#define WF_OFF   0        // W:  24 cb x 48 kb tiles = 589824
#define WPH_OFF  589824   // Wp hi: 2 ct x 48 kb = 49152
#define WPL_OFF  638976   // Wp lo: 49152
#define WCF_OFF  688128   // Wc: 24 cb x 3 kb = 36864   (total 724992 sh)

typedef short bf16x8 __attribute__((ext_vector_type(8)));
typedef float f32x16 __attribute__((ext_vector_type(16)));

__device__ __forceinline__ float bf2f(short u) {
    union { unsigned int i; float f; } v;
    v.i = ((unsigned int)(unsigned short)u) << 16;
    return v.f;
}
__device__ __forceinline__ short f2bf(float f) {
    union { float f; unsigned int i; } v; v.f = f;
    unsigned int r = v.i + 0x7FFFu + ((v.i >> 16) & 1u);  // RNE
    return (short)(r >> 16);
}

// ---------------------------------------------------------------- K0: pack
// 1320 fragment tiles: [0,1152) W, [1152,1248) Wp hi+lo, [1248,1320) Wc.
__global__ __launch_bounds__(256) void pack_kernel(
    const float* __restrict__ W, const float* __restrict__ Wp,
    const float* __restrict__ Wc, short* __restrict__ ws)
{
    const int gw = (blockIdx.x * 256 + threadIdx.x) >> 6;
    const int L  = threadIdx.x & 63;
    const int lm = L & 31, half = L >> 5;

    if (gw < 1152) {                       // W [768 x 768]
        const int cb = gw / 48, kb = gw % 48;
        const int row = cb * 32 + lm;
        const int k = kb * 16 + half * 8;
        bf16x8 o;
#pragma unroll
        for (int j = 0; j < 8; j++) o[j] = f2bf(W[(size_t)row * DIN + k + j]);
        *reinterpret_cast<bf16x8*>(&ws[WF_OFF + (size_t)gw * 512 + L * 8]) = o;
    } else if (gw < 1248) {                // Wp [48 x 768], hi/lo, pad rows->64
        const int t = gw - 1152;
        const int ct = t / 48, kb = t % 48;
        const int j = ct * 32 + lm;
        const int k = kb * 16 + half * 8;
        bf16x8 h, l;
#pragma unroll
        for (int jj = 0; jj < 8; jj++) {
            float v = (j < NWAV) ? Wp[(size_t)j * DIN + k + jj] : 0.f;
            const short hh = f2bf(v);
            h[jj] = hh;
            l[jj] = f2bf(v - bf2f(hh));
        }
        *reinterpret_cast<bf16x8*>(&ws[WPH_OFF + (size_t)t * 512 + L * 8]) = h;
        *reinterpret_cast<bf16x8*>(&ws[WPL_OFF + (size_t)t * 512 + L * 8]) = l;
    } else if (gw < 1320) {                // Wc [768 x 48]
        const int t = gw - 1248;
        const int cb = t / 3, kb = t % 3;
        const int row = cb * 32 + lm;
        const int k = kb * 16 + half * 8;
        bf16x8 o;
#pragma unroll
        for (int jj = 0; jj < 8; jj++) o[jj] = f2bf(Wc[(size_t)row * NWAV + k + jj]);
        *reinterpret_cast<bf16x8*>(&ws[WCF_OFF + (size_t)t * 512 + L * 8]) = o;
    }
}

// ---------------------------------------------------------------- K1: fused
__global__ __launch_bounds__(512, 2) void fused_kernel(
    const float* __restrict__ x, const short* __restrict__ ws,
    const float* __restrict__ Wp,
    const float* __restrict__ bp, const float* __restrict__ sc,
    const float* __restrict__ tr,
    const float* __restrict__ bb, const float* __restrict__ bc,
    const float* __restrict__ gm, const float* __restrict__ bt,
    float* __restrict__ out)
{
    // x tiles: 64 rows x 64 k bf16, row stride 72 shorts (144 B = 9 granules,
    // 9 coprime 8 -> conflict-free b128 frag reads). Double-buffered hi + lo.
    __shared__ __align__(16) short xh[2][64 * 72];
    __shared__ __align__(16) short xl[2][64 * 72];
    __shared__ float redS[64 * 8], redQ[64 * 8];
    __shared__ float muA[64], rsA[64];

    const short* WF  = ws + WF_OFF;
    const short* WPH = ws + WPH_OFF;
    const short* WPL = ws + WPL_OFF;
    const short* WCF = ws + WCF_OFF;

    const int tid = threadIdx.x;
    const int r0  = blockIdx.x * 64;
    const int wv  = tid >> 6, L = tid & 63;
    const int lm  = L & 31, half = L >> 5;

    f32x16 acc[2][3];                 // [rt (row 32-block)][ct (col 32-block)]
#pragma unroll
    for (int rt = 0; rt < 2; rt++)
#pragma unroll
        for (int ct = 0; ct < 3; ct++)
#pragma unroll
            for (int g = 0; g < 16; g++) acc[rt][ct][g] = 0.f;
    f32x16 wacc;                      // wi acc (waves 0-3)
#pragma unroll
    for (int g = 0; g < 16; g++) wacc[g] = 0.f;

    const int wrt = wv & 1, wct = wv >> 1;     // wi tile for wv<4

    // staging role: thread -> (row, 8-k chunk)
    const int srow = tid >> 3;
    const int sk   = (tid & 7) * 8;

    // ---- prologue: stage k0=0 into buf 0
    {
        const float4* xp = reinterpret_cast<const float4*>(&x[(size_t)(r0 + srow) * DIN + sk]);
        const float4 v0 = xp[0], v1 = xp[1];
        const float f[8] = {v0.x, v0.y, v0.z, v0.w, v1.x, v1.y, v1.z, v1.w};
        bf16x8 hh, ll;
#pragma unroll
        for (int i = 0; i < 8; i++) {
            const short h = f2bf(f[i]);
            hh[i] = h;
            ll[i] = f2bf(f[i] - bf2f(h));
        }
        *reinterpret_cast<bf16x8*>(&xh[0][srow * 72 + sk]) = hh;
        *reinterpret_cast<bf16x8*>(&xl[0][srow * 72 + sk]) = ll;
    }
    __syncthreads();

    // ---- K loop: 12 chunks of 64
    for (int k0i = 0; k0i < 12; ++k0i) {
        const int cur = k0i & 1;
        float4 v0, v1;
        if (k0i < 11) {  // prefetch next x chunk (completes under compute)
            const float4* xp = reinterpret_cast<const float4*>(
                &x[(size_t)(r0 + srow) * DIN + (k0i + 1) * 64 + sk]);
            v0 = xp[0]; v1 = xp[1];
        }
        const int kb0 = k0i * 4;

        // direct path: 2 rt x 3 ct x 4 ksteps
#pragma unroll
        for (int ks = 0; ks < 4; ++ks) {
            const bf16x8 a0 = *reinterpret_cast<bf16x8*>(&xh[cur][lm * 72 + ks * 16 + half * 8]);
            const bf16x8 a1 = *reinterpret_cast<bf16x8*>(&xh[cur][(32 + lm) * 72 + ks * 16 + half * 8]);
#pragma unroll
            for (int ct = 0; ct < 3; ++ct) {
                const bf16x8 b = *reinterpret_cast<const bf16x8*>(
                    &WF[((size_t)((wv * 3 + ct) * 48 + kb0 + ks)) * 512 + L * 8]);
                acc[0][ct] = __builtin_amdgcn_mfma_f32_32x32x16_bf16(a0, b, acc[0][ct], 0, 0, 0);
                acc[1][ct] = __builtin_amdgcn_mfma_f32_32x32x16_bf16(a1, b, acc[1][ct], 0, 0, 0);
            }
        }

        // wi path (waves 0-3): split-bf16, 3 MFMA per kstep
        if (wv < 4) {
#pragma unroll
            for (int ks = 0; ks < 4; ++ks) {
                const bf16x8 ah = *reinterpret_cast<bf16x8*>(&xh[cur][(wrt * 32 + lm) * 72 + ks * 16 + half * 8]);
                const bf16x8 al = *reinterpret_cast<bf16x8*>(&xl[cur][(wrt * 32 + lm) * 72 + ks * 16 + half * 8]);
                const bf16x8 bh = *reinterpret_cast<const bf16x8*>(
                    &WPH[((size_t)(wct * 48 + kb0 + ks)) * 512 + L * 8]);
                const bf16x8 bl = *reinterpret_cast<const bf16x8*>(
                    &WPL[((size_t)(wct * 48 + kb0 + ks)) * 512 + L * 8]);
                wacc = __builtin_amdgcn_mfma_f32_32x32x16_bf16(ah, bl, wacc, 0, 0, 0);
                wacc = __builtin_amdgcn_mfma_f32_32x32x16_bf16(al, bh, wacc, 0, 0, 0);
                wacc = __builtin_amdgcn_mfma_f32_32x32x16_bf16(ah, bh, wacc, 0, 0, 0);
            }
        }

        // stage next chunk into 1-cur (other waves only read cur this iter)
        if (k0i < 11) {
            const float f[8] = {v0.x, v0.y, v0.z, v0.w, v1.x, v1.y, v1.z, v1.w};
            bf16x8 hh, ll;
#pragma unroll
            for (int i = 0; i < 8; i++) {
                const short h = f2bf(f[i]);
                hh[i] = h;
                ll[i] = f2bf(f[i] - bf2f(h));
            }
            *reinterpret_cast<bf16x8*>(&xh[1 - cur][srow * 72 + sk]) = hh;
            *reinterpret_cast<bf16x8*>(&xl[1 - cur][srow * 72 + sk]) = ll;
        }
        __syncthreads();
    }

    // ---- wavelet activation + GELU -> wav tile in LDS (reuse xh[0])
    short* wavL = &xh[0][0];
    if (wv < 4) {
        const int j = wct * 32 + lm;
        if (j < NWAV) {
            const float bpv = bp[j], scv = sc[j], trv = tr[j];
#pragma unroll
            for (int g = 0; g < 16; ++g) {
                const int rowl = wrt * 32 + (g & 3) + 8 * (g >> 2) + 4 * half;  // C/D map
                const float wi = wacc[g] + bpv;
                const float s = (wi - trv) / scv;
                float w;
                if (j < 16) {
                    // haar: fp64 recheck inside 2e-4 boundary band
                    const float dmin = fminf(fabsf(s), fminf(fabsf(s - 0.5f), fabsf(s - 1.0f)));
                    if (dmin < 2e-4f) {
                        const float* xr = &x[(size_t)(r0 + rowl) * DIN];
                        const float* wr = &Wp[(size_t)j * DIN];
                        double a0 = 0.0, a1 = 0.0, a2 = 0.0, a3 = 0.0;
                        for (int k = 0; k < DIN; k += 4) {
                            a0 = fma((double)xr[k + 0], (double)wr[k + 0], a0);
                            a1 = fma((double)xr[k + 1], (double)wr[k + 1], a1);
                            a2 = fma((double)xr[k + 2], (double)wr[k + 2], a2);
                            a3 = fma((double)xr[k + 3], (double)wr[k + 3], a3);
                        }
                        const double wid = ((a0 + a1) + (a2 + a3)) + (double)bpv;
                        const double sd = (wid - (double)trv) / (double)scv;
                        w = (sd >= 0.0 && sd < 0.5) ? 1.f : ((sd >= 0.5 && sd < 1.0) ? -1.f : 0.f);
                    } else {
                        w = (s >= 0.f && s < 0.5f) ? 1.f : ((s >= 0.5f && s < 1.f) ? -1.f : 0.f);
                    }
                } else if (j < 32) {
                    w = (1.f - s * s) * expf(-0.5f * s * s);
                } else {
                    w = cosf(5.f * s) * expf(-0.5f * s * s);
                }
                const float gel = 0.5f * w * (1.f + erff(w * 0.70710678118654752f));
                wavL[rowl * 72 + j] = f2bf(gel);
            }
        }
    }
    __syncthreads();

    // ---- h += wav @ Wc^T  (K=48 -> 3 ksteps)
#pragma unroll
    for (int ks = 0; ks < 3; ++ks) {
        const bf16x8 a0 = *reinterpret_cast<bf16x8*>(&wavL[lm * 72 + ks * 16 + half * 8]);
        const bf16x8 a1 = *reinterpret_cast<bf16x8*>(&wavL[(32 + lm) * 72 + ks * 16 + half * 8]);
#pragma unroll
        for (int ct = 0; ct < 3; ++ct) {
            const bf16x8 b = *reinterpret_cast<const bf16x8*>(
                &WCF[((size_t)((wv * 3 + ct) * 3 + ks)) * 512 + L * 8]);
            acc[0][ct] = __builtin_amdgcn_mfma_f32_32x32x16_bf16(a0, b, acc[0][ct], 0, 0, 0);
            acc[1][ct] = __builtin_amdgcn_mfma_f32_32x32x16_bf16(a1, b, acc[1][ct], 0, 0, 0);
        }
    }

    // ---- bias + LN reduction
    float bias[3], gmv[3], btv[3];
#pragma unroll
    for (int ct = 0; ct < 3; ++ct) {
        const int col = wv * 96 + ct * 32 + lm;
        bias[ct] = bb[col] + bc[col];
        gmv[ct] = gm[col];
        btv[ct] = bt[col];
    }
#pragma unroll
    for (int rt = 0; rt < 2; ++rt) {
#pragma unroll
        for (int g = 0; g < 16; ++g) {
            const float v0 = acc[rt][0][g] + bias[0];
            const float v1 = acc[rt][1][g] + bias[1];
            const float v2 = acc[rt][2][g] + bias[2];
            acc[rt][0][g] = v0; acc[rt][1][g] = v1; acc[rt][2][g] = v2;
            float s1 = v0 + v1 + v2;
            float s2 = v0 * v0 + v1 * v1 + v2 * v2;
            // reduce across the 32 lanes of this half (same output row)
            s1 += __shfl_xor(s1, 1);  s2 += __shfl_xor(s2, 1);
            s1 += __shfl_xor(s1, 2);  s2 += __shfl_xor(s2, 2);
            s1 += __shfl_xor(s1, 4);  s2 += __shfl_xor(s2, 4);
            s1 += __shfl_xor(s1, 8);  s2 += __shfl_xor(s2, 8);
            s1 += __shfl_xor(s1, 16); s2 += __shfl_xor(s2, 16);
            if (lm == 0) {
                const int rowl = rt * 32 + (g & 3) + 8 * (g >> 2) + 4 * half;
                redS[rowl * 8 + wv] = s1;
                redQ[rowl * 8 + wv] = s2;
            }
        }
    }
    __syncthreads();
    if (tid < 64) {
        float S = 0.f, Q = 0.f;
#pragma unroll
        for (int i = 0; i < 8; i++) { S += redS[tid * 8 + i]; Q += redQ[tid * 8 + i]; }
        const float mu = S * (1.f / 768.f);
        const float var = Q * (1.f / 768.f) - mu * mu;
        muA[tid] = mu;
        rsA[tid] = rsqrtf(var + 1e-5f);
    }
    __syncthreads();

    // ---- normalize + store (f32)
#pragma unroll
    for (int rt = 0; rt < 2; ++rt) {
#pragma unroll
        for (int g = 0; g < 16; ++g) {
            const int rowl = rt * 32 + (g & 3) + 8 * (g >> 2) + 4 * half;
            const float mu = muA[rowl], rs = rsA[rowl];
            float* orow = &out[(size_t)(r0 + rowl) * DOUT + wv * 96 + lm];
#pragma unroll
            for (int ct = 0; ct < 3; ++ct) {
                orow[ct * 32] = (acc[rt][ct][g] - mu) * rs * gmv[ct] + btv[ct];
            }
        }
    }
}

// ---------------------------------------------------------------- launcher
extern "C" void kernel_launch(void* const* d_in, const int* in_sizes, int n_in,
                              void* d_out, int out_size, void* d_ws, size_t ws_size,
                              hipStream_t stream)
{
    const float* x  = (const float*)d_in[0];
    const float* W  = (const float*)d_in[1];
    const float* b  = (const float*)d_in[2];
    const float* Wp = (const float*)d_in[3];
    const float* bp = (const float*)d_in[4];
    const float* Wc = (const float*)d_in[5];
    const float* bc = (const float*)d_in[6];
    const float* sc = (const float*)d_in[7];
    const float* tr = (const float*)d_in[8];
    const float* gm = (const float*)d_in[9];
    const float* bt = (const float*)d_in[10];
    float* out = (float*)d_out;
    short* ws  = (short*)d_ws;   // ~1.42 MB of fragment-packed weights

    pack_kernel<<<dim3(330), dim3(256), 0, stream>>>(W, Wp, Wc, ws);
    fused_kernel<<<dim3(B_SZ / 64), dim3(512), 0, stream>>>(
        x, ws, Wp, bp, sc, tr, b, bc, gm, bt, out);
}